// Round 13
// baseline (99.101 us; speedup 1.0000x reference)
//
#include <hip/hip_runtime.h>
#include <math.h>

constexpr int H = 512, W = 512;
constexpr int N_ANGLES = 360;
constexpr int N_DET = 736;
constexpr int N_STEPS = 725;                 // ceil(hypot(512,512))
constexpr int SINO_SIZE = N_ANGLES * N_DET;  // 264960

constexpr int DET_TILE = 64;
constexpr int K_TILE   = 64;
constexpr int PITCH    = 100;  // dword cells; mult of 4 (16B chunks); need <= 97
constexpr int ROWS     = 93;
constexpr int QCHUNKS  = PITCH / 4;          // 25 16B-chunks/row (DMA path)
constexpr int MAXJ     = 5;                  // ceil(93*25/512)
// LDS: 93*100*4 = 37200 B -> 4 blocks/CU @ 512 thr

// padded f16-pair image (in d_ws): cell (y,x) = pack(v[y-PADY][x-PADX],
// v[y-PADY+1][x-PADX]) with v = zero-bordered x+reco.
constexpr int PADX = 96, PADY = 96;
constexpr int PW = 720;   // x0 in [-92,512] -> cols 4..707 < 720
constexpr int PH = 704;   // y0 in [-92,512] -> rows 4..700 < 704
constexpr size_t PAD_BYTES = (size_t)PW * PH * 4;

typedef float v2f __attribute__((ext_vector_type(2)));
typedef __fp16 h2f __attribute__((ext_vector_type(2)));
union PackU { unsigned u; h2f h; };

// ---------------------------------------------------------------------------
// Kernel 1a (DMA path): build f16 vertical-pair padded image + updated output.
// ---------------------------------------------------------------------------
__global__ void pad_kernel(const float* __restrict__ x,
                           const float* __restrict__ reco,
                           unsigned* __restrict__ padded2,
                           float* __restrict__ updated) {
    int i = blockIdx.x * blockDim.x + threadIdx.x;
    if (i >= PW * PH) return;
    int p = i / PW, q = i - p * PW;
    int gy = p - PADY, gx = q - PADX;
    float v0 = 0.0f, v1 = 0.0f;
    if ((unsigned)gx < (unsigned)W) {
        if ((unsigned)gy < (unsigned)H) {
            int gi = gy * W + gx;
            v0 = x[gi] + reco[gi];
            updated[gi] = v0;
        }
        if ((unsigned)(gy + 1) < (unsigned)H) {
            int gi = (gy + 1) * W + gx;
            v1 = x[gi] + reco[gi];
        }
    }
    PackU pk;
    pk.h = __builtin_amdgcn_cvt_pkrtz(v0, v1);
    padded2[i] = pk.u;
}

// ---------------------------------------------------------------------------
// Kernel 1b (fallback): updated = x + reco
// ---------------------------------------------------------------------------
__global__ void add_kernel(const float4* __restrict__ x,
                           const float4* __restrict__ reco,
                           float4* __restrict__ out) {
    int i = blockIdx.x * blockDim.x + threadIdx.x;
    float4 a = x[i];
    float4 b = reco[i];
    out[i] = make_float4(a.x + b.x, a.y + b.y, a.z + b.z, a.w + b.w);
}

// ---------------------------------------------------------------------------
// Kernel 2: forward projection (r4/r7 proven geometry + f16-pair cells).
// Block = (angle, 64 detectors), 512 threads; wave footprint 16 det x 4 k.
// DMA=true: stage f16-pair cells via global_load_lds w=16 (zero logic).
// Sample: ONE ds_read2_b32 (idx,idx+1): dword0=(v00,v10), dword1=(v01,v11)
//  -> 4x cvt f16->f32 -> packed-f32 lerp. Halves LDS dwords vs r12.
// DMA=false: VALU staging of the same cells from the raw image (bounds-checked).
// ---------------------------------------------------------------------------
template <bool DMA>
__global__ __launch_bounds__(512, 8) void radon_kernel(const void* __restrict__ imgv,
                                                       const float* __restrict__ angles,
                                                       float* __restrict__ sino) {
    __shared__ unsigned tile[ROWS * PITCH];

    const int tid = threadIdx.x;
    const int w   = tid >> 6;
    const int l   = tid & 63;
    const int dt_ = 16 * (w & 3) + (l & 15);   // detector within tile
    const int klr = 4 * (w >> 2) + (l >> 4);   // k residue 0..7
    const int a   = blockIdx.y;
    const int d0  = blockIdx.x * DET_TILE;

    const float theta = angles[a];
    const float c = cosf(theta);
    const float s = sinf(theta);
    const float ac = fabsf(c), as = fabsf(s);
    const float cx = (W - 1) * 0.5f;            // 255.5
    const float cy = (H - 1) * 0.5f;            // 255.5
    const float t_off = (N_STEPS - 1) * 0.5f;   // 362

    const float u   = (float)(d0 + dt_) - (N_DET - 1) * 0.5f;
    const float bxu = cx - s * u;               // px = c*t + bxu
    const float byu = cy + c * u;               // py = s*t + byu

    // ---- conservative block k-window via interval arithmetic over u ----
    const float uLo = (float)d0 - (N_DET - 1) * 0.5f;
    const float uHi = uLo + (DET_TILE - 1);
    float su0 = s * uLo, su1 = s * uHi;
    float smin = fminf(su0, su1), smax = fmaxf(su0, su1);
    float cu0 = c * uLo, cu1 = c * uHi;
    float cmin = fminf(cu0, cu1), cmax = fmaxf(cu0, cu1);

    float tmin = -1e30f, tmax = 1e30f;
    {   // exists u: px in (-1, W)  <=>  c*t in (xlo, xhi)
        float xlo = -1.0f - cx + smin;
        float xhi = (float)W - cx + smax;
        if (ac > 1e-12f) {
            float t0 = xlo / c, t1 = xhi / c;
            tmin = fmaxf(tmin, fminf(t0, t1));
            tmax = fminf(tmax, fmaxf(t0, t1));
        } else if (xlo > 0.0f || xhi < 0.0f) {
            tmax = -2e30f;
        }
    }
    {   // exists u: py in (-1, H)  <=>  s*t in (ylo, yhi)
        float ylo = -1.0f - cy - cmax;
        float yhi = (float)H - cy - cmin;
        if (as > 1e-12f) {
            float t0 = ylo / s, t1 = yhi / s;
            tmin = fmaxf(tmin, fminf(t0, t1));
            tmax = fminf(tmax, fmaxf(t0, t1));
        } else if (ylo > 0.0f || yhi < 0.0f) {
            tmax = -2e30f;
        }
    }
    const int kminU = (int)fminf(725.0f, fmaxf(0.0f, ceilf(tmin + t_off) - 1.0f));
    const int kmaxU = (int)fmaxf(-1.0f, fminf((float)(N_STEPS - 1), floorf(tmax + t_off) + 1.0f));

    const float ucf = uLo + 0.5f * (DET_TILE - 1);
    const v2f dinc = {8.0f * c, 8.0f * s};

    float acc = 0.0f;

    for (int k0 = kminU; k0 <= kmaxU; k0 += K_TILE) {
        const int k1 = min(k0 + K_TILE - 1, kmaxU);
        // ---- bbox of ALL sample positions for (u in tile, t in [t0,t1]) ----
        const float t0f = (float)k0 - t_off;
        const float dt  = (float)(k1 - k0);
        const float tc  = t0f + 0.5f * dt;
        const float xc_ = fmaf(c, tc, cx) - s * ucf;
        const float yc_ = fmaf(s, tc, cy) + c * ucf;
        const float hx = fmaf(0.5f * ac, dt, 0.5f * (DET_TILE - 1) * as) + 0.5f;
        const float hy = fmaf(0.5f * as, dt, 0.5f * (DET_TILE - 1) * ac) + 0.5f;
        const int x0 = ((int)floorf(xc_ - hx)) & ~3;     // 16B-chunk aligned
        const int y0 = (int)floorf(yc_ - hy);
        // cell row r covers image rows y0+r, y0+r+1; need rows up to floor(ymax)
        const int bh = min((int)floorf(yc_ + hy) + 1 - y0, ROWS);

        // ---- stage bh rows x PITCH cells ----
        if constexpr (DMA) {
            const unsigned* img2 = (const unsigned*)imgv;
            const int total = bh * QCHUNKS;
            const unsigned* srow = img2 + (size_t)(y0 + PADY) * PW + (x0 + PADX);
            #pragma unroll
            for (int j = 0; j < MAXJ; ++j) {
                const int i = tid + j * 512;
                if (i < total) {
                    const int r  = i / QCHUNKS;          // const-divisor magic mul
                    const int ch = i - r * QCHUNKS;
                    const unsigned* src = srow + r * PW + ch * 4;
                    unsigned* dst = tile + (size_t)(i & ~63) * 4;  // wave-uniform
                    __builtin_amdgcn_global_load_lds(
                        (const __attribute__((address_space(1))) unsigned*)src,
                        (__attribute__((address_space(3))) unsigned*)dst,
                        16, 0, 0);
                }
            }
        } else {
            const float* img = (const float*)imgv;
            const int total = bh * PITCH;
            for (int i = tid; i < total; i += 512) {
                int r  = i / PITCH;
                int gxx = i - r * PITCH + x0;
                int gy = y0 + r;
                float v0 = 0.0f, v1 = 0.0f;
                if ((unsigned)gxx < (unsigned)W) {
                    if ((unsigned)gy < (unsigned)H)       v0 = img[gy * W + gxx];
                    if ((unsigned)(gy + 1) < (unsigned)H) v1 = img[(gy + 1) * W + gxx];
                }
                PackU pk;
                pk.h = __builtin_amdgcn_cvt_pkrtz(v0, v1);
                tile[i] = pk.u;
            }
        }
        __syncthreads();   // drains vmcnt(0) before s_barrier

        // ---- branch-free sampling: ONE ds_read2_b32 per sample ----
        // px,py >= 0 by bbox construction -> truncation == floor, fract valid
        const int kst = k0 + klr;
        v2f pos = {fmaf(c, (float)kst - t_off, bxu) - (float)x0,
                   fmaf(s, (float)kst - t_off, byu) - (float)y0};
        #pragma unroll 4
        for (int k = kst; k <= k1; k += 8) {
            int xi = (int)pos.x;
            int yi = (int)pos.y;
            float wx = __builtin_amdgcn_fractf(pos.x);
            float wy = __builtin_amdgcn_fractf(pos.y);
            int idx = __mul24(yi, PITCH) + xi;
            PackU q0, q1;
            q0.u = tile[idx];                    // ds_read2_b32 (0,1)
            q1.u = tile[idx + 1];
            v2f c0 = {(float)q0.h.x, (float)q0.h.y};   // (v00, v10)
            v2f c1 = {(float)q1.h.x, (float)q1.h.y};   // (v01, v11)
            v2f diff = c1 - c0;
            v2f wx2 = {wx, wx};
            v2f tb = __builtin_elementwise_fma(wx2, diff, c0);  // (top, bot)
            acc = fmaf(wy, tb.y - tb.x, acc + tb.x);
            pos += dinc;
        }
        __syncthreads();
    }

    // ---- reduce 8 k-residues per detector ----
    acc += __shfl_xor(acc, 16);
    acc += __shfl_xor(acc, 32);
    float* scratch = (float*)tile;
    if (l < 16) scratch[w * 16 + l] = acc;
    __syncthreads();
    if (tid < DET_TILE) {
        int g  = tid >> 4;
        int dd = tid & 15;
        float r = scratch[g * 16 + dd] + scratch[(g + 4) * 16 + dd];
        int dglob = d0 + tid;
        if (dglob < N_DET) sino[a * N_DET + dglob] = r;   // dets 736..767 phantom
    }
}

// ---------------------------------------------------------------------------
extern "C" void kernel_launch(void* const* d_in, const int* in_sizes, int n_in,
                              void* d_out, int out_size, void* d_ws, size_t ws_size,
                              hipStream_t stream) {
    const float* x      = (const float*)d_in[0];
    const float* reco   = (const float*)d_in[1];
    const float* angles = (const float*)d_in[2];

    float* sino    = (float*)d_out;              // (360, 736)
    float* updated = (float*)d_out + SINO_SIZE;  // (512, 512)

    dim3 grid((N_DET + DET_TILE - 1) / DET_TILE, N_ANGLES);   // (12, 360)

    if (ws_size >= PAD_BYTES) {
        unsigned* padded2 = (unsigned*)d_ws;
        pad_kernel<<<(PW * PH + 255) / 256, 256, 0, stream>>>(x, reco, padded2, updated);
        radon_kernel<true><<<grid, 512, 0, stream>>>(padded2, angles, sino);
    } else {
        int n4 = (H * W) / 4;
        add_kernel<<<n4 / 256, 256, 0, stream>>>(
            (const float4*)x, (const float4*)reco, (float4*)updated);
        radon_kernel<false><<<grid, 512, 0, stream>>>(updated, angles, sino);
    }
}